// Round 4
// baseline (275.052 us; speedup 1.0000x reference)
//
#include <hip/hip_runtime.h>
#include <hip/hip_bf16.h>
#include <stdint.h>

typedef __attribute__((ext_vector_type(8))) __bf16 bf16x8;
typedef __attribute__((ext_vector_type(4))) __bf16 bf16x4;
typedef __attribute__((ext_vector_type(4))) float f32x4;

#define DEV __device__ __forceinline__

static constexpr int S = 2048, F = 2048, H = 16, D = 128;
static constexpr int KDIM = F;            // 2048
static constexpr float QSCALE = 0.08838834764831845f;  // 1/sqrt(128)

DEV void gll16(const void* g, void* l) {
  __builtin_amdgcn_global_load_lds(
      (const __attribute__((address_space(1))) void*)g,
      (__attribute__((address_space(3))) void*)l, 16, 0, 0);
}

DEV f32x4 mfma16(bf16x8 a, bf16x8 b, f32x4 c) {
  return __builtin_amdgcn_mfma_f32_16x16x32_bf16(a, b, c, 0, 0, 0);
}

extern __shared__ char smem[];

// ---------------- elementwise f32 -> bf16 ----------------
__global__ void k_cvt(const float* __restrict__ in, __bf16* __restrict__ out) {
  int i = blockIdx.x * 256 + threadIdx.x;
  float4 v = reinterpret_cast<const float4*>(in)[i];
  bf16x4 o = {(__bf16)v.x, (__bf16)v.y, (__bf16)v.z, (__bf16)v.w};
  reinterpret_cast<bf16x4*>(out)[i] = o;
}

// ---------------- transpose f32 [rows][cols] -> bf16 [cols][rows] ----------------
__global__ void k_transpose(const float* __restrict__ in, __bf16* __restrict__ out,
                            int rows, int cols) {
  __shared__ float t[64][65];
  const int c0 = blockIdx.x * 64, r0 = blockIdx.y * 64;
  const int tx = threadIdx.x & 63, ty = threadIdx.x >> 6;
#pragma unroll
  for (int i = 0; i < 64; i += 4)
    t[ty + i][tx] = in[(size_t)(r0 + ty + i) * cols + c0 + tx];
  __syncthreads();
#pragma unroll
  for (int i = 0; i < 64; i += 4)
    out[(size_t)(c0 + ty + i) * rows + r0 + tx] = (__bf16)t[tx][ty + i];
}

// ================= QKV GEMM: 256x384 tile, BK=64, double-buffered =================
// C[M,N] = A[M,K]*Bt[N,K]^T + bias, routed to Q(scaled)/K/V^T. Grid 256 = 1/CU exact.
// 8 waves (2M x 4N), wave tile 128x96, acc[8][6]. LDS 2 x 80 KiB {A:[256][64] 32K,
// B:[384][64] 48K}, chunk-XOR swizzled. 2 phases/K-tile, stage split 6/4, ONE
// barrier + vmcnt(0) per tile (dbuf: outstanding == next tile's 10 loads).
__global__ __launch_bounds__(512, 2) void k_qkv(
    const __bf16* __restrict__ A, const __bf16* __restrict__ Bt,
    const float* __restrict__ bias,
    __bf16* __restrict__ qo, __bf16* __restrict__ ko, __bf16* __restrict__ vo) {
  const int tid = threadIdx.x;
  const int lane = tid & 63, wid = tid >> 6;
  const int wm = wid >> 2, wn = wid & 3;
  const int ln = lane & 15, lm = lane >> 4;

  // XCD swizzle: 256 blocks -> XCD x owns lin [32x,32x+32) = by{2x,2x+1} x all bx.
  const int lin = (blockIdx.x & 7) * 32 + (blockIdx.x >> 3);
  const int by = lin >> 4, bx = lin & 15;
  const int mBase = by * 256, nBase = bx * 384;

  // stage source: chunk c = j*512+tid; r = tid>>3 + j*64; cc = tid&7 (j*512%8==0).
  // swz constant across j -> ONE offset + j*131072 elements.
  const int r0 = tid >> 3, cc = tid & 7;
  const int src0 = r0 * KDIM + ((cc ^ (r0 & 7)) << 3);
  const __bf16* Ab = A + (size_t)mBase * KDIM + src0;
  const __bf16* Bb = Bt + (size_t)nBase * KDIM + src0;
  const int dstBase = wid * 1024;  // + lane*16 by HW

  // ds_read byte offsets (slot = logical chunk ^ (row&7); row&7 == ln&7)
  int rA[2], rB[2];
#pragma unroll
  for (int ks = 0; ks < 2; ++ks) {
    const int slot = (ks * 4 + lm) ^ (ln & 7);
    rA[ks] = (wm * 128 + ln) * 128 + slot * 16;
    rB[ks] = 32768 + (wn * 96 + ln) * 128 + slot * 16;
  }

  f32x4 acc[8][6] = {};
  constexpr int NT = KDIM / 64;  // 32

  // prologue: stage tile 0 into buf 0 (10 loads)
#pragma unroll
  for (int j = 0; j < 4; ++j) gll16(Ab + j * 131072, smem + j * 8192 + dstBase);
#pragma unroll
  for (int j = 0; j < 6; ++j) gll16(Bb + j * 131072, smem + 32768 + j * 8192 + dstBase);
  asm volatile("s_waitcnt vmcnt(0)" ::: "memory");
  __builtin_amdgcn_s_barrier();
  __builtin_amdgcn_sched_barrier(0);

  for (int t = 0; t < NT; ++t) {
    const int cur = t & 1;
    const char* cb = smem + cur * 81920;
    char* nb = smem + (cur ^ 1) * 81920;
    const __bf16* An = Ab + (t + 1) * 64;
    const __bf16* Bn = Bb + (t + 1) * 64;
    const bool pf = (t + 1 < NT);

    // ---- phase ks=0: reads + stage A(4)+B(2) + 48 MFMA ----
    {
      bf16x8 a[8], b[6];
#pragma unroll
      for (int mi = 0; mi < 8; ++mi)
        a[mi] = *reinterpret_cast<const bf16x8*>(cb + rA[0] + mi * 2048);
#pragma unroll
      for (int ni = 0; ni < 6; ++ni)
        b[ni] = *reinterpret_cast<const bf16x8*>(cb + rB[0] + ni * 2048);
      if (pf) {
#pragma unroll
        for (int j = 0; j < 4; ++j) gll16(An + j * 131072, nb + j * 8192 + dstBase);
#pragma unroll
        for (int j = 0; j < 2; ++j) gll16(Bn + j * 131072, nb + 32768 + j * 8192 + dstBase);
      }
      asm volatile("s_waitcnt lgkmcnt(0)" ::: "memory");
      __builtin_amdgcn_sched_barrier(0);
      __builtin_amdgcn_s_setprio(1);
#pragma unroll
      for (int ni = 0; ni < 6; ++ni)
#pragma unroll
        for (int mi = 0; mi < 8; ++mi)
          acc[mi][ni] = mfma16(a[mi], b[ni], acc[mi][ni]);
      __builtin_amdgcn_s_setprio(0);
    }

    // ---- phase ks=1: reads + stage B(4) + 48 MFMA ----
    {
      bf16x8 a[8], b[6];
#pragma unroll
      for (int mi = 0; mi < 8; ++mi)
        a[mi] = *reinterpret_cast<const bf16x8*>(cb + rA[1] + mi * 2048);
#pragma unroll
      for (int ni = 0; ni < 6; ++ni)
        b[ni] = *reinterpret_cast<const bf16x8*>(cb + rB[1] + ni * 2048);
      if (pf) {
#pragma unroll
        for (int j = 2; j < 6; ++j) gll16(Bn + j * 131072, nb + 32768 + j * 8192 + dstBase);
      }
      asm volatile("s_waitcnt lgkmcnt(0)" ::: "memory");
      __builtin_amdgcn_sched_barrier(0);
      __builtin_amdgcn_s_setprio(1);
#pragma unroll
      for (int ni = 0; ni < 6; ++ni)
#pragma unroll
        for (int mi = 0; mi < 8; ++mi)
          acc[mi][ni] = mfma16(a[mi], b[ni], acc[mi][ni]);
      __builtin_amdgcn_s_setprio(0);
    }

    // ---- tile boundary: next tile landed, then rendezvous ----
    asm volatile("s_waitcnt vmcnt(0)" ::: "memory");
    __builtin_amdgcn_s_barrier();
    __builtin_amdgcn_sched_barrier(0);
  }

  // epilogue: route Q (scaled), K, V^T; section can change within the 384-col tile
#pragma unroll
  for (int mi = 0; mi < 8; ++mi) {
    const int grow = mBase + wm * 128 + mi * 16 + lm * 4;
    const int b = grow >> 11, s0 = grow & 2047;
#pragma unroll
    for (int ni = 0; ni < 6; ++ni) {
      const int gcol = nBase + wn * 96 + ni * 16 + ln;
      const float bv = bias[gcol];
      const int sec = gcol >> 11;            // uniform across the 16-lane col group
      const int h = (gcol >> 7) & 15, d = gcol & 127;
      const int bh = b * H + h;
      if (sec == 0) {
#pragma unroll
        for (int r = 0; r < 4; ++r)
          qo[((size_t)bh * S + s0 + r) * D + d] = (__bf16)((acc[mi][ni][r] + bv) * QSCALE);
      } else if (sec == 1) {
#pragma unroll
        for (int r = 0; r < 4; ++r)
          ko[((size_t)bh * S + s0 + r) * D + d] = (__bf16)(acc[mi][ni][r] + bv);
      } else {
        bf16x4 pv = {(__bf16)(acc[mi][ni][0] + bv), (__bf16)(acc[mi][ni][1] + bv),
                     (__bf16)(acc[mi][ni][2] + bv), (__bf16)(acc[mi][ni][3] + bv)};
        *reinterpret_cast<bf16x4*>(vo + ((size_t)bh * D + d) * S + s0) = pv;  // V^T
      }
    }
  }
}

// ================= out-proj: 128x256 triple-buffered GEMM (round-3 kernel) =================
__global__ __launch_bounds__(512, 2) void k_proj(
    const __bf16* __restrict__ A, const __bf16* __restrict__ Bt,
    const float* __restrict__ bias, float* __restrict__ fo, int nbx) {
  const int tid = threadIdx.x;
  const int lane = tid & 63, wid = tid >> 6;
  const int wm = wid >> 2, wn = wid & 3;
  const int ln = lane & 15, lm = lane >> 4;

  const int q8 = gridDim.x >> 3;
  const int lin = (blockIdx.x & 7) * q8 + (blockIdx.x >> 3);
  const int bx = lin % nbx, by = lin / nbx;
  const int mBase = by * 128, nBase = bx * 256;

  int srcA[2], dstA[2], srcB[4], dstB[4];
#pragma unroll
  for (int j = 0; j < 2; ++j) {
    int c = j * 512 + tid, r = c >> 3, cc = c & 7;
    srcA[j] = r * KDIM + ((cc ^ (r & 7)) << 3);
    dstA[j] = j * 8192 + wid * 1024;
  }
#pragma unroll
  for (int j = 0; j < 4; ++j) {
    int c = j * 512 + tid, r = c >> 3, cc = c & 7;
    srcB[j] = r * KDIM + ((cc ^ (r & 7)) << 3);
    dstB[j] = 16384 + j * 8192 + wid * 1024;
  }
  const __bf16* Ab = A + (size_t)mBase * KDIM;
  const __bf16* Bb = Bt + (size_t)nBase * KDIM;

  int loA[2], loB[2];
#pragma unroll
  for (int ks = 0; ks < 2; ++ks) {
    int slot = (ks * 4 + lm) ^ (ln & 7);
    loA[ks] = (wm * 64 + ln) * 128 + slot * 16;
    loB[ks] = 16384 + (wn * 64 + ln) * 128 + slot * 16;
  }

  f32x4 acc[4][4] = {};
  constexpr int NT = KDIM / 64;  // 32

#pragma unroll
  for (int j = 0; j < 2; ++j) gll16(Ab + srcA[j], smem + dstA[j]);
#pragma unroll
  for (int j = 0; j < 4; ++j) gll16(Bb + srcB[j], smem + dstB[j]);
#pragma unroll
  for (int j = 0; j < 2; ++j) gll16(Ab + 64 + srcA[j], smem + 49152 + dstA[j]);
#pragma unroll
  for (int j = 0; j < 4; ++j) gll16(Bb + 64 + srcB[j], smem + 49152 + dstB[j]);
  asm volatile("s_waitcnt vmcnt(6)" ::: "memory");
  __builtin_amdgcn_s_barrier();
  __builtin_amdgcn_sched_barrier(0);

  for (int t = 0; t < NT; ++t) {
    const char* cbuf = smem + (t % 3) * 49152;
    char* nbuf = smem + ((t + 2) % 3) * 49152;
    const __bf16* Asrc = Ab + (t + 2) * 64;
    const __bf16* Bsrc = Bb + (t + 2) * 64;
    const bool pf = (t + 2 < NT);

    bf16x8 af0[4], bf0[4];
#pragma unroll
    for (int mi = 0; mi < 4; ++mi)
      af0[mi] = *reinterpret_cast<const bf16x8*>(cbuf + mi * 2048 + loA[0]);
#pragma unroll
    for (int ni = 0; ni < 4; ++ni)
      bf0[ni] = *reinterpret_cast<const bf16x8*>(cbuf + ni * 2048 + loB[0]);
    if (pf) {
      gll16(Asrc + srcA[0], nbuf + dstA[0]);
      gll16(Asrc + srcA[1], nbuf + dstA[1]);
      gll16(Bsrc + srcB[0], nbuf + dstB[0]);
    }
    __builtin_amdgcn_s_setprio(1);
#pragma unroll
    for (int mi = 0; mi < 4; ++mi)
#pragma unroll
      for (int ni = 0; ni < 4; ++ni)
        acc[mi][ni] = mfma16(af0[mi], bf0[ni], acc[mi][ni]);
    __builtin_amdgcn_s_setprio(0);

    bf16x8 af1[4], bf1[4];
#pragma unroll
    for (int mi = 0; mi < 4; ++mi)
      af1[mi] = *reinterpret_cast<const bf16x8*>(cbuf + mi * 2048 + loA[1]);
#pragma unroll
    for (int ni = 0; ni < 4; ++ni)
      bf1[ni] = *reinterpret_cast<const bf16x8*>(cbuf + ni * 2048 + loB[1]);
    if (pf) {
      gll16(Bsrc + srcB[1], nbuf + dstB[1]);
      gll16(Bsrc + srcB[2], nbuf + dstB[2]);
      gll16(Bsrc + srcB[3], nbuf + dstB[3]);
    }
    __builtin_amdgcn_s_setprio(1);
#pragma unroll
    for (int mi = 0; mi < 4; ++mi)
#pragma unroll
      for (int ni = 0; ni < 4; ++ni)
        acc[mi][ni] = mfma16(af1[mi], bf1[ni], acc[mi][ni]);
    __builtin_amdgcn_s_setprio(0);

    if (t < NT - 2)
      asm volatile("s_waitcnt vmcnt(6) lgkmcnt(0)" ::: "memory");
    else
      asm volatile("s_waitcnt vmcnt(0) lgkmcnt(0)" ::: "memory");
    __builtin_amdgcn_s_barrier();
    __builtin_amdgcn_sched_barrier(0);
  }

#pragma unroll
  for (int mi = 0; mi < 4; ++mi) {
    const int grow = mBase + wm * 64 + mi * 16 + lm * 4;
#pragma unroll
    for (int ni = 0; ni < 4; ++ni) {
      const int gcol = nBase + wn * 64 + ni * 16 + ln;
      const float bv = bias[gcol];
#pragma unroll
      for (int r = 0; r < 4; ++r)
        fo[(size_t)(grow + r) * F + gcol] = acc[mi][ni][r] + bv;
    }
  }
}

// ---------------- flash attention: 4 waves x 32 q-rows, KVBLK=64 ----------------
__global__ __launch_bounds__(256, 2) void k_attn(
    const __bf16* __restrict__ qb, const __bf16* __restrict__ kb,
    const __bf16* __restrict__ vtb, __bf16* __restrict__ zb) {
  const int lane = threadIdx.x & 63, w = threadIdx.x >> 6;
  const int lm = lane >> 4, ln = lane & 15;
  const int blk = blockIdx.x;
  const int bh = blk & 31;
  const int qt = 15 - (blk >> 5);
  const int qw = qt * 128 + w * 32;

  const __bf16* qp = qb + (size_t)bh * S * D;
  const __bf16* kp = kb + (size_t)bh * S * D;
  const __bf16* vp = vtb + (size_t)bh * D * S;
  char* pw = smem + 65536 + w * 4096;

  int ksrc[4], kdst[4], vsrc[4], vdst[4];
#pragma unroll
  for (int j = 0; j < 4; ++j) {
    int c = (w * 4 + j) * 64 + lane;
    int kr = c >> 4, kps = (c & 15) ^ (kr & 7);
    ksrc[j] = kr * D + kps * 8;
    kdst[j] = (w * 4 + j) * 1024;
    int vr = c >> 3, vps = (c & 7) ^ (vr & 7);
    vsrc[j] = vr * S + vps * 8;
    vdst[j] = 16384 + (w * 4 + j) * 1024;
  }

  bf16x8 qf[2][4];
#pragma unroll
  for (int mi = 0; mi < 2; ++mi)
#pragma unroll
    for (int kf = 0; kf < 4; ++kf)
      qf[mi][kf] = *reinterpret_cast<const bf16x8*>(qp + (qw + mi * 16 + ln) * D + kf * 32 + lm * 8);

  f32x4 Oa[2][8] = {};
  float mrow[2][4], lrow[2][4];
#pragma unroll
  for (int mi = 0; mi < 2; ++mi)
#pragma unroll
    for (int r = 0; r < 4; ++r) { mrow[mi][r] = -3.0e38f; lrow[mi][r] = 0.0f; }

  const int ktEnd = 2 * qt + 1;

#pragma unroll
  for (int j = 0; j < 4; ++j) gll16(kp + ksrc[j], smem + kdst[j]);
#pragma unroll
  for (int j = 0; j < 4; ++j) gll16(vp + vsrc[j], smem + vdst[j]);
  asm volatile("s_waitcnt vmcnt(0)" ::: "memory");
  __builtin_amdgcn_s_barrier();
  __builtin_amdgcn_sched_barrier(0);

  for (int kt = 0; kt <= ktEnd; ++kt) {
    const int kv0 = kt * 64;
    const int cur = kt & 1;

    if (kt < ktEnd) {
      const int nk = (kt + 1) * 64;
      char* nbuf = smem + (cur ^ 1) * 32768;
#pragma unroll
      for (int j = 0; j < 4; ++j) gll16(kp + (size_t)nk * D + ksrc[j], nbuf + kdst[j]);
#pragma unroll
      for (int j = 0; j < 4; ++j) gll16(vp + nk + vsrc[j], nbuf + vdst[j]);
    }

    if (kv0 <= qw + 31) {
      const char* Kb = smem + cur * 32768;
      const char* Vb = Kb + 16384;
      const bool diag = (kv0 + 63 > qw);

      f32x4 sacc[2][4] = {};
#pragma unroll
      for (int kf = 0; kf < 4; ++kf) {
        bf16x8 kfr[4];
#pragma unroll
        for (int ni = 0; ni < 4; ++ni) {
          int row = ni * 16 + ln;
          int ch = (kf * 4 + lm) ^ (row & 7);
          kfr[ni] = *reinterpret_cast<const bf16x8*>(Kb + row * 256 + ch * 16);
        }
        __builtin_amdgcn_s_setprio(1);
#pragma unroll
        for (int mi = 0; mi < 2; ++mi)
#pragma unroll
          for (int ni = 0; ni < 4; ++ni)
            sacc[mi][ni] = mfma16(qf[mi][kf], kfr[ni], sacc[mi][ni]);
        __builtin_amdgcn_s_setprio(0);
      }

      if (diag) {
#pragma unroll
        for (int ni = 0; ni < 4; ++ni) {
          int c = kv0 + ni * 16 + ln;
#pragma unroll
          for (int mi = 0; mi < 2; ++mi) {
            int q0r = qw + mi * 16 + lm * 4;
#pragma unroll
            for (int r = 0; r < 4; ++r)
              if (c > q0r + r) sacc[mi][ni][r] = -1e30f;
          }
        }
      }

#pragma unroll
      for (int mi = 0; mi < 2; ++mi)
#pragma unroll
        for (int r = 0; r < 4; ++r) {
          float mx = fmaxf(fmaxf(sacc[mi][0][r], sacc[mi][1][r]),
                           fmaxf(sacc[mi][2][r], sacc[mi][3][r]));
          mx = fmaxf(mx, __shfl_xor(mx, 1, 64));
          mx = fmaxf(mx, __shfl_xor(mx, 2, 64));
          mx = fmaxf(mx, __shfl_xor(mx, 4, 64));
          mx = fmaxf(mx, __shfl_xor(mx, 8, 64));
          float mnew = fmaxf(mrow[mi][r], mx);
          float corr = __expf(mrow[mi][r] - mnew);
          mrow[mi][r] = mnew;
          float rs = 0.0f;
#pragma unroll
          for (int ni = 0; ni < 4; ++ni) {
            float p = __expf(sacc[mi][ni][r] - mnew);
            sacc[mi][ni][r] = p;
            rs += p;
          }
          lrow[mi][r] = lrow[mi][r] * corr + rs;
#pragma unroll
          for (int ni = 0; ni < 8; ++ni) Oa[mi][ni][r] *= corr;
        }

#pragma unroll
      for (int mi = 0; mi < 2; ++mi)
#pragma unroll
        for (int ni = 0; ni < 4; ++ni)
#pragma unroll
          for (int r = 0; r < 4; ++r) {
            int row = mi * 16 + lm * 4 + r;
            int bo = (row * 128 + (ni * 16 + ln) * 2) ^ ((row & 7) << 4);
            *reinterpret_cast<__bf16*>(pw + bo) = (__bf16)sacc[mi][ni][r];
          }

      asm volatile("s_waitcnt lgkmcnt(0)" ::: "memory");
      __builtin_amdgcn_sched_barrier(0);

#pragma unroll
      for (int kf = 0; kf < 2; ++kf) {
        bf16x8 pfr[2], vfr[8];
#pragma unroll
        for (int mi = 0; mi < 2; ++mi) {
          int row = mi * 16 + ln;
          int ch = (kf * 4 + lm) ^ (row & 7);
          pfr[mi] = *reinterpret_cast<const bf16x8*>(pw + row * 128 + ch * 16);
        }
#pragma unroll
        for (int ni = 0; ni < 8; ++ni) {
          int row = ni * 16 + ln;
          int ch = (kf * 4 + lm) ^ (row & 7);
          vfr[ni] = *reinterpret_cast<const bf16x8*>(Vb + row * 128 + ch * 16);
        }
        __builtin_amdgcn_s_setprio(1);
#pragma unroll
        for (int mi = 0; mi < 2; ++mi)
#pragma unroll
          for (int ni = 0; ni < 8; ++ni)
            Oa[mi][ni] = mfma16(pfr[mi], vfr[ni], Oa[mi][ni]);
        __builtin_amdgcn_s_setprio(0);
      }
    }

    asm volatile("s_waitcnt vmcnt(0) lgkmcnt(0)" ::: "memory");
    __builtin_amdgcn_s_barrier();
    __builtin_amdgcn_sched_barrier(0);
  }

#pragma unroll
  for (int mi = 0; mi < 2; ++mi)
#pragma unroll
    for (int r = 0; r < 4; ++r) {
      float ls = lrow[mi][r];
      ls += __shfl_xor(ls, 1, 64);
      ls += __shfl_xor(ls, 2, 64);
      ls += __shfl_xor(ls, 4, 64);
      ls += __shfl_xor(ls, 8, 64);
      lrow[mi][r] = 1.0f / ls;
    }
  const int b = bh >> 4, h = bh & 15;
#pragma unroll
  for (int mi = 0; mi < 2; ++mi)
#pragma unroll
    for (int ni = 0; ni < 8; ++ni) {
      int d = ni * 16 + ln;
#pragma unroll
      for (int r = 0; r < 4; ++r) {
        int qrow = qw + mi * 16 + lm * 4 + r;
        zb[(size_t)(b * S + qrow) * F + h * D + d] = (__bf16)(Oa[mi][ni][r] * lrow[mi][r]);
      }
    }
}

// ---------------- launch ----------------
extern "C" void kernel_launch(void* const* d_in, const int* in_sizes, int n_in,
                              void* d_out, int out_size, void* d_ws, size_t ws_size,
                              hipStream_t stream) {
  const float* x = (const float*)d_in[0];
  // d_in[1] = causal mask (implemented analytically)
  const float* w_attn = (const float*)d_in[2];
  const float* b_attn = (const float*)d_in[3];
  const float* w_proj = (const float*)d_in[4];
  const float* b_proj = (const float*)d_in[5];
  float* out = (float*)d_out;

  char* ws = (char*)d_ws;
  __bf16* xb    = (__bf16*)(ws + 0);          // 16 MB  [4096][2048] (reused as zb)
  __bf16* wqkv  = (__bf16*)(ws + 16777216);   // 24 MB  [6144][2048] (W^T)
  __bf16* wpro  = (__bf16*)(ws + 41943040);   //  8 MB  [2048][2048] (W^T)
  __bf16* qb    = (__bf16*)(ws + 50331648);   // 16 MB  [bh][s][d]
  __bf16* kb    = (__bf16*)(ws + 67108864);   // 16 MB  [bh][s][d]
  __bf16* vtb   = (__bf16*)(ws + 83886080);   // 16 MB  [bh][d][s]
  __bf16* zb    = xb;  // x fully consumed by QKV GEMM before attention writes z

  (void)hipFuncSetAttribute((const void*)k_qkv,
                            hipFuncAttributeMaxDynamicSharedMemorySize, 163840);
  (void)hipFuncSetAttribute((const void*)k_proj,
                            hipFuncAttributeMaxDynamicSharedMemorySize, 147456);
  (void)hipFuncSetAttribute((const void*)k_attn,
                            hipFuncAttributeMaxDynamicSharedMemorySize, 81920);

  k_cvt<<<8192, 256, 0, stream>>>(x, xb);
  k_transpose<<<dim3(96, 32), 256, 0, stream>>>(w_attn, wqkv, 2048, 6144);
  k_transpose<<<dim3(32, 32), 256, 0, stream>>>(w_proj, wpro, 2048, 2048);
  // QKV: M=4096 (16 x 256), N=6144 (16 x 384) -> 256 blocks = 1/CU exact
  k_qkv<<<256, 512, 163840, stream>>>(xb, wqkv, b_attn, qb, kb, vtb);
  // attention: 512 blocks (LPT + XCD-affinity remap inside)
  k_attn<<<512, 256, 81920, stream>>>(qb, kb, vtb, zb);
  // out-proj: M=4096, N=2048 -> 32x8 = 256 blocks = 1/CU exact
  k_proj<<<256, 512, 147456, stream>>>(zb, wpro, b_proj, out, 8);
}

// Round 5
// 266.753 us; speedup vs baseline: 1.0311x; 1.0311x over previous
//
#include <hip/hip_runtime.h>
#include <hip/hip_bf16.h>
#include <stdint.h>

typedef __attribute__((ext_vector_type(8))) __bf16 bf16x8;
typedef __attribute__((ext_vector_type(4))) __bf16 bf16x4;
typedef __attribute__((ext_vector_type(4))) float f32x4;

#define DEV __device__ __forceinline__

static constexpr int S = 2048, F = 2048, H = 16, D = 128;
static constexpr int KDIM = F;            // 2048
static constexpr float QSCALE = 0.08838834764831845f;  // 1/sqrt(128)

DEV void gll16(const void* g, void* l) {
  __builtin_amdgcn_global_load_lds(
      (const __attribute__((address_space(1))) void*)g,
      (__attribute__((address_space(3))) void*)l, 16, 0, 0);
}

DEV f32x4 mfma16(bf16x8 a, bf16x8 b, f32x4 c) {
  return __builtin_amdgcn_mfma_f32_16x16x32_bf16(a, b, c, 0, 0, 0);
}

extern __shared__ char smem[];

// ---------------- elementwise f32 -> bf16 ----------------
__global__ void k_cvt(const float* __restrict__ in, __bf16* __restrict__ out) {
  int i = blockIdx.x * 256 + threadIdx.x;
  float4 v = reinterpret_cast<const float4*>(in)[i];
  bf16x4 o = {(__bf16)v.x, (__bf16)v.y, (__bf16)v.z, (__bf16)v.w};
  reinterpret_cast<bf16x4*>(out)[i] = o;
}

// ---------------- transpose f32 [rows][cols] -> bf16 [cols][rows] ----------------
__global__ void k_transpose(const float* __restrict__ in, __bf16* __restrict__ out,
                            int rows, int cols) {
  __shared__ float t[64][65];
  const int c0 = blockIdx.x * 64, r0 = blockIdx.y * 64;
  const int tx = threadIdx.x & 63, ty = threadIdx.x >> 6;
#pragma unroll
  for (int i = 0; i < 64; i += 4)
    t[ty + i][tx] = in[(size_t)(r0 + ty + i) * cols + c0 + tx];
  __syncthreads();
#pragma unroll
  for (int i = 0; i < 64; i += 4)
    out[(size_t)(c0 + ty + i) * rows + r0 + tx] = (__bf16)t[tx][ty + i];
}

// ================= deep-pipelined GEMM: BMxBN tile, BK=64, dbuf + counted vmcnt ====
// C[M,N] = A[M,K]*Bt[N,K]^T + bias. 8 waves (2M x 4N), wave tile (BM/2)x(BN/4).
// LDS 2 bufs x (BM+BN)*128 B, chunk-XOR swizzled (source pre-swizzled, rule 21).
// KEY (T4): after phase-1 reads retire + barrier, buf `cur` is dead -> stage ALL of
// tile t+2 into it BEFORE the boundary; boundary waits vmcnt(NL) = "t+1 landed"
// (issued a full tile earlier) -> near-free. Never drains to 0 in steady state.
// EPI 0: route Q(scaled)/K/V^T bf16.  EPI 1: f32 +bias.
template <int BM, int BN, int NBXL, int EPI>
__global__ __launch_bounds__(512, 2) void k_gp(
    const __bf16* __restrict__ A, const __bf16* __restrict__ Bt,
    const float* __restrict__ bias,
    __bf16* __restrict__ qo, __bf16* __restrict__ ko, __bf16* __restrict__ vo,
    float* __restrict__ fo) {
  constexpr int MF = BM / 32;        // A frags per ks (wave tile rows / 16)
  constexpr int NF = BN / 64;        // B frags per ks
  constexpr int NLA = BM / 64;       // A stage loads (8 KB each)
  constexpr int NLB = BN / 64;       // B stage loads
  constexpr int NL = NLA + NLB;
  constexpr int AOFF = BM * 128;     // bytes: B region offset in a buffer
  constexpr int BUFSZ = (BM + BN) * 128;
  constexpr int NT = KDIM / 64;      // 32

  const int tid = threadIdx.x;
  const int lane = tid & 63, wid = tid >> 6;
  const int wm = wid >> 2, wn = wid & 3;
  const int ln = lane & 15, lm = lane >> 4;

  // T1: XCD-aware bijective swizzle (gridDim.x == 256)
  const int lin = (blockIdx.x & 7) * 32 + (blockIdx.x >> 3);
  const int by = lin >> NBXL, bx = lin & ((1 << NBXL) - 1);
  const int mBase = by * BM, nBase = bx * BN;

  // stage source: chunk c = j*512+tid; row r = j*64 + (tid>>3); col-chunk cc = tid&7.
  // swizzle constant across j (r&7 invariant) -> one base + j*64 rows.
  const int r0 = tid >> 3, cc = tid & 7;
  const int src0 = r0 * KDIM + ((cc ^ (r0 & 7)) << 3);
  const __bf16* Ab = A + (size_t)mBase * KDIM + src0;
  const __bf16* Bb = Bt + (size_t)nBase * KDIM + src0;
  const int dstBase = wid * 1024;  // + lane*16 by HW

  auto stage = [&](char* buf, int t) {
    const __bf16* As = Ab + t * 64;
    const __bf16* Bs = Bb + t * 64;
#pragma unroll
    for (int j = 0; j < NLA; ++j)
      gll16(As + (size_t)j * 64 * KDIM, buf + j * 8192 + dstBase);
#pragma unroll
    for (int j = 0; j < NLB; ++j)
      gll16(Bs + (size_t)j * 64 * KDIM, buf + AOFF + j * 8192 + dstBase);
  };

  // ds_read byte offsets (slot = logical chunk ^ (row&7); row&7 == ln&7)
  int rA[2], rB[2];
#pragma unroll
  for (int ks = 0; ks < 2; ++ks) {
    const int slot = (ks * 4 + lm) ^ (ln & 7);
    rA[ks] = (wm * (BM / 2) + ln) * 128 + slot * 16;
    rB[ks] = AOFF + (wn * (BN / 4) + ln) * 128 + slot * 16;
  }

  f32x4 acc[MF][NF] = {};

  // prologue: stage tiles 0 and 1
  stage(smem, 0);
  stage(smem + BUFSZ, 1);
  if constexpr (NL == 10) asm volatile("s_waitcnt vmcnt(10)" ::: "memory");
  else                    asm volatile("s_waitcnt vmcnt(6)" ::: "memory");
  __builtin_amdgcn_s_barrier();
  __builtin_amdgcn_sched_barrier(0);

  for (int t = 0; t < NT; ++t) {
    char* cb = smem + (t & 1) * BUFSZ;

    // ---- phase ks=0: reads + MFMA ----
    {
      bf16x8 a[MF], b[NF];
#pragma unroll
      for (int mi = 0; mi < MF; ++mi)
        a[mi] = *reinterpret_cast<const bf16x8*>(cb + rA[0] + mi * 2048);
#pragma unroll
      for (int ni = 0; ni < NF; ++ni)
        b[ni] = *reinterpret_cast<const bf16x8*>(cb + rB[0] + ni * 2048);
      asm volatile("s_waitcnt lgkmcnt(0)" ::: "memory");
      __builtin_amdgcn_sched_barrier(0);
      __builtin_amdgcn_s_setprio(1);
#pragma unroll
      for (int ni = 0; ni < NF; ++ni)
#pragma unroll
        for (int mi = 0; mi < MF; ++mi)
          acc[mi][ni] = mfma16(a[mi], b[ni], acc[mi][ni]);
      __builtin_amdgcn_s_setprio(0);
    }

    // ---- phase ks=1: reads, then buf `cur` is dead -> stage t+2 into it ----
    {
      bf16x8 a[MF], b[NF];
#pragma unroll
      for (int mi = 0; mi < MF; ++mi)
        a[mi] = *reinterpret_cast<const bf16x8*>(cb + rA[1] + mi * 2048);
#pragma unroll
      for (int ni = 0; ni < NF; ++ni)
        b[ni] = *reinterpret_cast<const bf16x8*>(cb + rB[1] + ni * 2048);
      asm volatile("s_waitcnt lgkmcnt(0)" ::: "memory");
      __builtin_amdgcn_sched_barrier(0);
      __builtin_amdgcn_s_barrier();      // all waves' reads of cb retired
      if (t + 2 < NT) stage(cb, t + 2);  // WAR-safe: issues after the barrier
      __builtin_amdgcn_sched_barrier(0);
      __builtin_amdgcn_s_setprio(1);
#pragma unroll
      for (int ni = 0; ni < NF; ++ni)
#pragma unroll
        for (int mi = 0; mi < MF; ++mi)
          acc[mi][ni] = mfma16(a[mi], b[ni], acc[mi][ni]);
      __builtin_amdgcn_s_setprio(0);
    }

    // ---- boundary: t+1 landed (counted wait), rendezvous ----
    if (t + 2 < NT) {
      if constexpr (NL == 10) asm volatile("s_waitcnt vmcnt(10)" ::: "memory");
      else                    asm volatile("s_waitcnt vmcnt(6)" ::: "memory");
    } else if (t + 1 < NT) {
      asm volatile("s_waitcnt vmcnt(0)" ::: "memory");
    }
    if (t + 1 < NT) {
      __builtin_amdgcn_s_barrier();
      __builtin_amdgcn_sched_barrier(0);
    }
  }

  if (EPI == 0) {
#pragma unroll
    for (int mi = 0; mi < MF; ++mi) {
      const int grow = mBase + wm * (BM / 2) + mi * 16 + lm * 4;
      const int b = grow >> 11, s0 = grow & 2047;
#pragma unroll
      for (int ni = 0; ni < NF; ++ni) {
        const int gcol = nBase + wn * (BN / 4) + ni * 16 + ln;
        const float bv = bias[gcol];
        const int sec = gcol >> 11;  // uniform across the 16-lane col group
        const int h = (gcol >> 7) & 15, d = gcol & 127;
        const int bh = b * H + h;
        if (sec == 0) {
#pragma unroll
          for (int r = 0; r < 4; ++r)
            qo[((size_t)bh * S + s0 + r) * D + d] = (__bf16)((acc[mi][ni][r] + bv) * QSCALE);
        } else if (sec == 1) {
#pragma unroll
          for (int r = 0; r < 4; ++r)
            ko[((size_t)bh * S + s0 + r) * D + d] = (__bf16)(acc[mi][ni][r] + bv);
        } else {
          bf16x4 pv = {(__bf16)(acc[mi][ni][0] + bv), (__bf16)(acc[mi][ni][1] + bv),
                       (__bf16)(acc[mi][ni][2] + bv), (__bf16)(acc[mi][ni][3] + bv)};
          *reinterpret_cast<bf16x4*>(vo + ((size_t)bh * D + d) * S + s0) = pv;  // V^T
        }
      }
    }
  } else {
#pragma unroll
    for (int mi = 0; mi < MF; ++mi) {
      const int grow = mBase + wm * (BM / 2) + mi * 16 + lm * 4;
#pragma unroll
      for (int ni = 0; ni < NF; ++ni) {
        const int gcol = nBase + wn * (BN / 4) + ni * 16 + ln;
        const float bv = bias[gcol];
#pragma unroll
        for (int r = 0; r < 4; ++r)
          fo[(size_t)(grow + r) * F + gcol] = acc[mi][ni][r] + bv;
      }
    }
  }
}

// ---------------- flash attention: 4 waves x 32 q-rows, KVBLK=64 ----------------
__global__ __launch_bounds__(256, 2) void k_attn(
    const __bf16* __restrict__ qb, const __bf16* __restrict__ kb,
    const __bf16* __restrict__ vtb, __bf16* __restrict__ zb) {
  const int lane = threadIdx.x & 63, w = threadIdx.x >> 6;
  const int lm = lane >> 4, ln = lane & 15;
  const int blk = blockIdx.x;
  const int bh = blk & 31;
  const int qt = 15 - (blk >> 5);
  const int qw = qt * 128 + w * 32;

  const __bf16* qp = qb + (size_t)bh * S * D;
  const __bf16* kp = kb + (size_t)bh * S * D;
  const __bf16* vp = vtb + (size_t)bh * D * S;
  char* pw = smem + 65536 + w * 4096;

  int ksrc[4], kdst[4], vsrc[4], vdst[4];
#pragma unroll
  for (int j = 0; j < 4; ++j) {
    int c = (w * 4 + j) * 64 + lane;
    int kr = c >> 4, kps = (c & 15) ^ (kr & 7);
    ksrc[j] = kr * D + kps * 8;
    kdst[j] = (w * 4 + j) * 1024;
    int vr = c >> 3, vps = (c & 7) ^ (vr & 7);
    vsrc[j] = vr * S + vps * 8;
    vdst[j] = 16384 + (w * 4 + j) * 1024;
  }

  bf16x8 qf[2][4];
#pragma unroll
  for (int mi = 0; mi < 2; ++mi)
#pragma unroll
    for (int kf = 0; kf < 4; ++kf)
      qf[mi][kf] = *reinterpret_cast<const bf16x8*>(qp + (qw + mi * 16 + ln) * D + kf * 32 + lm * 8);

  f32x4 Oa[2][8] = {};
  float mrow[2][4], lrow[2][4];
#pragma unroll
  for (int mi = 0; mi < 2; ++mi)
#pragma unroll
    for (int r = 0; r < 4; ++r) { mrow[mi][r] = -3.0e38f; lrow[mi][r] = 0.0f; }

  const int ktEnd = 2 * qt + 1;

#pragma unroll
  for (int j = 0; j < 4; ++j) gll16(kp + ksrc[j], smem + kdst[j]);
#pragma unroll
  for (int j = 0; j < 4; ++j) gll16(vp + vsrc[j], smem + vdst[j]);
  asm volatile("s_waitcnt vmcnt(0)" ::: "memory");
  __builtin_amdgcn_s_barrier();
  __builtin_amdgcn_sched_barrier(0);

  for (int kt = 0; kt <= ktEnd; ++kt) {
    const int kv0 = kt * 64;
    const int cur = kt & 1;

    if (kt < ktEnd) {
      const int nk = (kt + 1) * 64;
      char* nbuf = smem + (cur ^ 1) * 32768;
#pragma unroll
      for (int j = 0; j < 4; ++j) gll16(kp + (size_t)nk * D + ksrc[j], nbuf + kdst[j]);
#pragma unroll
      for (int j = 0; j < 4; ++j) gll16(vp + nk + vsrc[j], nbuf + vdst[j]);
    }

    if (kv0 <= qw + 31) {
      const char* Kb = smem + cur * 32768;
      const char* Vb = Kb + 16384;
      const bool diag = (kv0 + 63 > qw);

      f32x4 sacc[2][4] = {};
#pragma unroll
      for (int kf = 0; kf < 4; ++kf) {
        bf16x8 kfr[4];
#pragma unroll
        for (int ni = 0; ni < 4; ++ni) {
          int row = ni * 16 + ln;
          int ch = (kf * 4 + lm) ^ (row & 7);
          kfr[ni] = *reinterpret_cast<const bf16x8*>(Kb + row * 256 + ch * 16);
        }
        __builtin_amdgcn_s_setprio(1);
#pragma unroll
        for (int mi = 0; mi < 2; ++mi)
#pragma unroll
          for (int ni = 0; ni < 4; ++ni)
            sacc[mi][ni] = mfma16(qf[mi][kf], kfr[ni], sacc[mi][ni]);
        __builtin_amdgcn_s_setprio(0);
      }

      if (diag) {
#pragma unroll
        for (int ni = 0; ni < 4; ++ni) {
          int c = kv0 + ni * 16 + ln;
#pragma unroll
          for (int mi = 0; mi < 2; ++mi) {
            int q0r = qw + mi * 16 + lm * 4;
#pragma unroll
            for (int r = 0; r < 4; ++r)
              if (c > q0r + r) sacc[mi][ni][r] = -1e30f;
          }
        }
      }

#pragma unroll
      for (int mi = 0; mi < 2; ++mi)
#pragma unroll
        for (int r = 0; r < 4; ++r) {
          float mx = fmaxf(fmaxf(sacc[mi][0][r], sacc[mi][1][r]),
                           fmaxf(sacc[mi][2][r], sacc[mi][3][r]));
          mx = fmaxf(mx, __shfl_xor(mx, 1, 64));
          mx = fmaxf(mx, __shfl_xor(mx, 2, 64));
          mx = fmaxf(mx, __shfl_xor(mx, 4, 64));
          mx = fmaxf(mx, __shfl_xor(mx, 8, 64));
          float mnew = fmaxf(mrow[mi][r], mx);
          float corr = __expf(mrow[mi][r] - mnew);
          mrow[mi][r] = mnew;
          float rs = 0.0f;
#pragma unroll
          for (int ni = 0; ni < 4; ++ni) {
            float p = __expf(sacc[mi][ni][r] - mnew);
            sacc[mi][ni][r] = p;
            rs += p;
          }
          lrow[mi][r] = lrow[mi][r] * corr + rs;
#pragma unroll
          for (int ni = 0; ni < 8; ++ni) Oa[mi][ni][r] *= corr;
        }

#pragma unroll
      for (int mi = 0; mi < 2; ++mi)
#pragma unroll
        for (int ni = 0; ni < 4; ++ni)
#pragma unroll
          for (int r = 0; r < 4; ++r) {
            int row = mi * 16 + lm * 4 + r;
            int bo = (row * 128 + (ni * 16 + ln) * 2) ^ ((row & 7) << 4);
            *reinterpret_cast<__bf16*>(pw + bo) = (__bf16)sacc[mi][ni][r];
          }

      asm volatile("s_waitcnt lgkmcnt(0)" ::: "memory");
      __builtin_amdgcn_sched_barrier(0);

#pragma unroll
      for (int kf = 0; kf < 2; ++kf) {
        bf16x8 pfr[2], vfr[8];
#pragma unroll
        for (int mi = 0; mi < 2; ++mi) {
          int row = mi * 16 + ln;
          int ch = (kf * 4 + lm) ^ (row & 7);
          pfr[mi] = *reinterpret_cast<const bf16x8*>(pw + row * 128 + ch * 16);
        }
#pragma unroll
        for (int ni = 0; ni < 8; ++ni) {
          int row = ni * 16 + ln;
          int ch = (kf * 4 + lm) ^ (row & 7);
          vfr[ni] = *reinterpret_cast<const bf16x8*>(Vb + row * 128 + ch * 16);
        }
        __builtin_amdgcn_s_setprio(1);
#pragma unroll
        for (int mi = 0; mi < 2; ++mi)
#pragma unroll
          for (int ni = 0; ni < 8; ++ni)
            Oa[mi][ni] = mfma16(pfr[mi], vfr[ni], Oa[mi][ni]);
        __builtin_amdgcn_s_setprio(0);
      }
    }

    asm volatile("s_waitcnt vmcnt(0) lgkmcnt(0)" ::: "memory");
    __builtin_amdgcn_s_barrier();
    __builtin_amdgcn_sched_barrier(0);
  }

#pragma unroll
  for (int mi = 0; mi < 2; ++mi)
#pragma unroll
    for (int r = 0; r < 4; ++r) {
      float ls = lrow[mi][r];
      ls += __shfl_xor(ls, 1, 64);
      ls += __shfl_xor(ls, 2, 64);
      ls += __shfl_xor(ls, 4, 64);
      ls += __shfl_xor(ls, 8, 64);
      lrow[mi][r] = 1.0f / ls;
    }
  const int b = bh >> 4, h = bh & 15;
#pragma unroll
  for (int mi = 0; mi < 2; ++mi)
#pragma unroll
    for (int ni = 0; ni < 8; ++ni) {
      int d = ni * 16 + ln;
#pragma unroll
      for (int r = 0; r < 4; ++r) {
        int qrow = qw + mi * 16 + lm * 4 + r;
        zb[(size_t)(b * S + qrow) * F + h * D + d] = (__bf16)(Oa[mi][ni][r] * lrow[mi][r]);
      }
    }
}

// ---------------- launch ----------------
extern "C" void kernel_launch(void* const* d_in, const int* in_sizes, int n_in,
                              void* d_out, int out_size, void* d_ws, size_t ws_size,
                              hipStream_t stream) {
  const float* x = (const float*)d_in[0];
  // d_in[1] = causal mask (implemented analytically)
  const float* w_attn = (const float*)d_in[2];
  const float* b_attn = (const float*)d_in[3];
  const float* w_proj = (const float*)d_in[4];
  const float* b_proj = (const float*)d_in[5];
  float* out = (float*)d_out;

  char* ws = (char*)d_ws;
  __bf16* xb    = (__bf16*)(ws + 0);          // 16 MB  [4096][2048] (reused as zb)
  __bf16* wqkv  = (__bf16*)(ws + 16777216);   // 24 MB  [6144][2048] (W^T)
  __bf16* wpro  = (__bf16*)(ws + 41943040);   //  8 MB  [2048][2048] (W^T)
  __bf16* qb    = (__bf16*)(ws + 50331648);   // 16 MB  [bh][s][d]
  __bf16* kb    = (__bf16*)(ws + 67108864);   // 16 MB  [bh][s][d]
  __bf16* vtb   = (__bf16*)(ws + 83886080);   // 16 MB  [bh][d][s]
  __bf16* zb    = xb;  // x fully consumed by QKV GEMM before attention writes z

  (void)hipFuncSetAttribute((const void*)k_gp<256, 384, 4, 0>,
                            hipFuncAttributeMaxDynamicSharedMemorySize, 163840);
  (void)hipFuncSetAttribute((const void*)k_gp<128, 256, 3, 1>,
                            hipFuncAttributeMaxDynamicSharedMemorySize, 98304);
  (void)hipFuncSetAttribute((const void*)k_attn,
                            hipFuncAttributeMaxDynamicSharedMemorySize, 81920);

  k_cvt<<<8192, 256, 0, stream>>>(x, xb);
  k_transpose<<<dim3(96, 32), 256, 0, stream>>>(w_attn, wqkv, 2048, 6144);
  k_transpose<<<dim3(32, 32), 256, 0, stream>>>(w_proj, wpro, 2048, 2048);
  // QKV: M=4096 (16 x 256), N=6144 (16 x 384) -> 256 blocks = 1/CU exact
  k_gp<256, 384, 4, 0><<<256, 512, 163840, stream>>>(xb, wqkv, b_attn, qb, kb, vtb, nullptr);
  // attention: 512 blocks (LPT + XCD-affinity remap inside)
  k_attn<<<512, 256, 81920, stream>>>(qb, kb, vtb, zb);
  // out-proj: M=4096 (32 x 128), N=2048 (8 x 256) -> 256 blocks = 1/CU exact
  k_gp<128, 256, 3, 1><<<256, 512, 98304, stream>>>(zb, wpro, b_proj, nullptr, nullptr, nullptr, out);
}

// Round 6
// 257.327 us; speedup vs baseline: 1.0689x; 1.0366x over previous
//
#include <hip/hip_runtime.h>
#include <hip/hip_bf16.h>
#include <stdint.h>

typedef __attribute__((ext_vector_type(8))) __bf16 bf16x8;
typedef __attribute__((ext_vector_type(4))) __bf16 bf16x4;
typedef __attribute__((ext_vector_type(4))) float f32x4;

#define DEV __device__ __forceinline__

static constexpr int S = 2048, F = 2048, H = 16, D = 128;
static constexpr int KDIM = F;            // 2048
static constexpr float QSCALE = 0.08838834764831845f;  // 1/sqrt(128)

DEV void gll16(const void* g, void* l) {
  __builtin_amdgcn_global_load_lds(
      (const __attribute__((address_space(1))) void*)g,
      (__attribute__((address_space(3))) void*)l, 16, 0, 0);
}

DEV f32x4 mfma16(bf16x8 a, bf16x8 b, f32x4 c) {
  return __builtin_amdgcn_mfma_f32_16x16x32_bf16(a, b, c, 0, 0, 0);
}

extern __shared__ char smem[];

// ---------------- elementwise f32 -> bf16 ----------------
__global__ void k_cvt(const float* __restrict__ in, __bf16* __restrict__ out) {
  int i = blockIdx.x * 256 + threadIdx.x;
  float4 v = reinterpret_cast<const float4*>(in)[i];
  bf16x4 o = {(__bf16)v.x, (__bf16)v.y, (__bf16)v.z, (__bf16)v.w};
  reinterpret_cast<bf16x4*>(out)[i] = o;
}

// ---------------- transpose f32 [rows][cols] -> bf16 [cols][rows] ----------------
__global__ void k_transpose(const float* __restrict__ in, __bf16* __restrict__ out,
                            int rows, int cols) {
  __shared__ float t[64][65];
  const int c0 = blockIdx.x * 64, r0 = blockIdx.y * 64;
  const int tx = threadIdx.x & 63, ty = threadIdx.x >> 6;
#pragma unroll
  for (int i = 0; i < 64; i += 4)
    t[ty + i][tx] = in[(size_t)(r0 + ty + i) * cols + c0 + tx];
  __syncthreads();
#pragma unroll
  for (int i = 0; i < 64; i += 4)
    out[(size_t)(c0 + ty + i) * rows + r0 + tx] = (__bf16)t[tx][ty + i];
}

// ================= deep-pipelined GEMM: BMxBN tile, BK=64, dbuf + counted vmcnt ====
// C[M,N] = A[M,K]*Bt[N,K]^T + bias. 8 waves (2M x 4N), wave tile (BM/2)x(BN/4).
// LDS 2 bufs x (BM+BN)*128 B, chunk-XOR swizzled (source pre-swizzled, rule 21).
// T4: after phase-1 reads retire + barrier, buf `cur` is dead -> stage ALL of tile
// t+2 into it; boundary waits vmcnt(NL) = "t+1 landed" (issued a full tile ago).
// __launch_bounds__(512, 1): do NOT cap VGPR at 128 (r4/r5 spilled acc to scratch:
// VGPR_Count=128 + ~42 MB extra WRITE_SIZE).
// EPI 0: route Q(scaled)/K/V^T bf16.  EPI 1: f32 +bias.
template <int BM, int BN, int NBXL, int EPI>
__global__ __launch_bounds__(512, 1) void k_gp(
    const __bf16* __restrict__ A, const __bf16* __restrict__ Bt,
    const float* __restrict__ bias,
    __bf16* __restrict__ qo, __bf16* __restrict__ ko, __bf16* __restrict__ vo,
    float* __restrict__ fo) {
  constexpr int MF = BM / 32;        // A frags per ks (wave tile rows / 16)
  constexpr int NF = BN / 64;        // B frags per ks
  constexpr int NLA = BM / 64;       // A stage loads (8 KB each)
  constexpr int NLB = BN / 64;       // B stage loads
  constexpr int NL = NLA + NLB;
  constexpr int AOFF = BM * 128;     // bytes: B region offset in a buffer
  constexpr int BUFSZ = (BM + BN) * 128;
  constexpr int NT = KDIM / 64;      // 32

  const int tid = threadIdx.x;
  const int lane = tid & 63, wid = tid >> 6;
  const int wm = wid >> 2, wn = wid & 3;
  const int ln = lane & 15, lm = lane >> 4;

  // T1: XCD-aware bijective swizzle (gridDim.x % 8 == 0)
  const int q8 = gridDim.x >> 3;
  const int lin = (blockIdx.x & 7) * q8 + (blockIdx.x >> 3);
  const int by = lin >> NBXL, bx = lin & ((1 << NBXL) - 1);
  const int mBase = by * BM, nBase = bx * BN;

  // stage source: chunk c = j*512+tid; row r = j*64 + (tid>>3); col-chunk cc = tid&7.
  // swizzle constant across j (r&7 invariant) -> one base + j*64 rows.
  const int r0 = tid >> 3, cc = tid & 7;
  const int src0 = r0 * KDIM + ((cc ^ (r0 & 7)) << 3);
  const __bf16* Ab = A + (size_t)mBase * KDIM + src0;
  const __bf16* Bb = Bt + (size_t)nBase * KDIM + src0;
  const int dstBase = wid * 1024;  // + lane*16 by HW

  auto stage = [&](char* buf, int t) {
    const __bf16* As = Ab + t * 64;
    const __bf16* Bs = Bb + t * 64;
#pragma unroll
    for (int j = 0; j < NLA; ++j)
      gll16(As + (size_t)j * 64 * KDIM, buf + j * 8192 + dstBase);
#pragma unroll
    for (int j = 0; j < NLB; ++j)
      gll16(Bs + (size_t)j * 64 * KDIM, buf + AOFF + j * 8192 + dstBase);
  };
  auto wait_nl = [&]() {  // vmcnt(NL): everything older than the newest NL landed
    if constexpr (NL == 6)       asm volatile("s_waitcnt vmcnt(6)" ::: "memory");
    else if constexpr (NL == 8)  asm volatile("s_waitcnt vmcnt(8)" ::: "memory");
    else                         asm volatile("s_waitcnt vmcnt(10)" ::: "memory");
  };

  // ds_read byte offsets (slot = logical chunk ^ (row&7); row&7 == ln&7)
  int rA[2], rB[2];
#pragma unroll
  for (int ks = 0; ks < 2; ++ks) {
    const int slot = (ks * 4 + lm) ^ (ln & 7);
    rA[ks] = (wm * (BM / 2) + ln) * 128 + slot * 16;
    rB[ks] = AOFF + (wn * (BN / 4) + ln) * 128 + slot * 16;
  }

  f32x4 acc[MF][NF] = {};

  // prologue: stage tiles 0 and 1
  stage(smem, 0);
  stage(smem + BUFSZ, 1);
  wait_nl();
  __builtin_amdgcn_s_barrier();
  __builtin_amdgcn_sched_barrier(0);

  for (int t = 0; t < NT; ++t) {
    char* cb = smem + (t & 1) * BUFSZ;

    // ---- phase ks=0: reads + MFMA ----
    {
      bf16x8 a[MF], b[NF];
#pragma unroll
      for (int mi = 0; mi < MF; ++mi)
        a[mi] = *reinterpret_cast<const bf16x8*>(cb + rA[0] + mi * 2048);
#pragma unroll
      for (int ni = 0; ni < NF; ++ni)
        b[ni] = *reinterpret_cast<const bf16x8*>(cb + rB[0] + ni * 2048);
      asm volatile("s_waitcnt lgkmcnt(0)" ::: "memory");
      __builtin_amdgcn_sched_barrier(0);
      __builtin_amdgcn_s_setprio(1);
#pragma unroll
      for (int ni = 0; ni < NF; ++ni)
#pragma unroll
        for (int mi = 0; mi < MF; ++mi)
          acc[mi][ni] = mfma16(a[mi], b[ni], acc[mi][ni]);
      __builtin_amdgcn_s_setprio(0);
    }

    // ---- phase ks=1: reads, then buf `cur` is dead -> stage t+2 into it ----
    {
      bf16x8 a[MF], b[NF];
#pragma unroll
      for (int mi = 0; mi < MF; ++mi)
        a[mi] = *reinterpret_cast<const bf16x8*>(cb + rA[1] + mi * 2048);
#pragma unroll
      for (int ni = 0; ni < NF; ++ni)
        b[ni] = *reinterpret_cast<const bf16x8*>(cb + rB[1] + ni * 2048);
      asm volatile("s_waitcnt lgkmcnt(0)" ::: "memory");
      __builtin_amdgcn_sched_barrier(0);
      __builtin_amdgcn_s_barrier();      // all waves' reads of cb retired
      if (t + 2 < NT) stage(cb, t + 2);  // WAR-safe: issues after the barrier
      __builtin_amdgcn_sched_barrier(0);
      __builtin_amdgcn_s_setprio(1);
#pragma unroll
      for (int ni = 0; ni < NF; ++ni)
#pragma unroll
        for (int mi = 0; mi < MF; ++mi)
          acc[mi][ni] = mfma16(a[mi], b[ni], acc[mi][ni]);
      __builtin_amdgcn_s_setprio(0);
    }

    // ---- boundary: t+1 landed (counted wait), rendezvous ----
    if (t + 2 < NT) {
      wait_nl();
    } else if (t + 1 < NT) {
      asm volatile("s_waitcnt vmcnt(0)" ::: "memory");
    }
    if (t + 1 < NT) {
      __builtin_amdgcn_s_barrier();
      __builtin_amdgcn_sched_barrier(0);
    }
  }

  if (EPI == 0) {
#pragma unroll
    for (int mi = 0; mi < MF; ++mi) {
      const int grow = mBase + wm * (BM / 2) + mi * 16 + lm * 4;
      const int b = grow >> 11, s0 = grow & 2047;
#pragma unroll
      for (int ni = 0; ni < NF; ++ni) {
        const int gcol = nBase + wn * (BN / 4) + ni * 16 + ln;
        const float bv = bias[gcol];
        const int sec = gcol >> 11;  // uniform across the 16-lane col group
        const int h = (gcol >> 7) & 15, d = gcol & 127;
        const int bh = b * H + h;
        if (sec == 0) {
#pragma unroll
          for (int r = 0; r < 4; ++r)
            qo[((size_t)bh * S + s0 + r) * D + d] = (__bf16)((acc[mi][ni][r] + bv) * QSCALE);
        } else if (sec == 1) {
#pragma unroll
          for (int r = 0; r < 4; ++r)
            ko[((size_t)bh * S + s0 + r) * D + d] = (__bf16)(acc[mi][ni][r] + bv);
        } else {
          bf16x4 pv = {(__bf16)(acc[mi][ni][0] + bv), (__bf16)(acc[mi][ni][1] + bv),
                       (__bf16)(acc[mi][ni][2] + bv), (__bf16)(acc[mi][ni][3] + bv)};
          *reinterpret_cast<bf16x4*>(vo + ((size_t)bh * D + d) * S + s0) = pv;  // V^T
        }
      }
    }
  } else {
#pragma unroll
    for (int mi = 0; mi < MF; ++mi) {
      const int grow = mBase + wm * (BM / 2) + mi * 16 + lm * 4;
#pragma unroll
      for (int ni = 0; ni < NF; ++ni) {
        const int gcol = nBase + wn * (BN / 4) + ni * 16 + ln;
        const float bv = bias[gcol];
#pragma unroll
        for (int r = 0; r < 4; ++r)
          fo[(size_t)(grow + r) * F + gcol] = acc[mi][ni][r] + bv;
      }
    }
  }
}

// ---------------- flash attention: 4 waves x 32 q-rows, KVBLK=64 ----------------
// 2 blocks/CU (80 KiB LDS each). Makespan-balanced remap: co-resident pair
// (blk, blk+256) gets complementary qt (sum 15 -> 34 tile-works per CU pair vs 48
// before). Per-bh XCD affinity preserved (all qt of one bh share blk&7).
__global__ __launch_bounds__(256, 2) void k_attn(
    const __bf16* __restrict__ qb, const __bf16* __restrict__ kb,
    const __bf16* __restrict__ vtb, __bf16* __restrict__ zb) {
  const int lane = threadIdx.x & 63, w = threadIdx.x >> 6;
  const int lm = lane >> 4, ln = lane & 15;
  const int blk = blockIdx.x;
  const int u = blk & 255, v = blk >> 8;
  const int qt = v ? (u >> 4) : 15 - (u >> 4);
  const int bh = ((u & 15) << 1) | v;
  const int qw = qt * 128 + w * 32;

  const __bf16* qp = qb + (size_t)bh * S * D;
  const __bf16* kp = kb + (size_t)bh * S * D;
  const __bf16* vp = vtb + (size_t)bh * D * S;
  char* pw = smem + 65536 + w * 4096;

  int ksrc[4], kdst[4], vsrc[4], vdst[4];
#pragma unroll
  for (int j = 0; j < 4; ++j) {
    int c = (w * 4 + j) * 64 + lane;
    int kr = c >> 4, kps = (c & 15) ^ (kr & 7);
    ksrc[j] = kr * D + kps * 8;
    kdst[j] = (w * 4 + j) * 1024;
    int vr = c >> 3, vps = (c & 7) ^ (vr & 7);
    vsrc[j] = vr * S + vps * 8;
    vdst[j] = 16384 + (w * 4 + j) * 1024;
  }

  bf16x8 qf[2][4];
#pragma unroll
  for (int mi = 0; mi < 2; ++mi)
#pragma unroll
    for (int kf = 0; kf < 4; ++kf)
      qf[mi][kf] = *reinterpret_cast<const bf16x8*>(qp + (qw + mi * 16 + ln) * D + kf * 32 + lm * 8);

  f32x4 Oa[2][8] = {};
  float mrow[2][4], lrow[2][4];
#pragma unroll
  for (int mi = 0; mi < 2; ++mi)
#pragma unroll
    for (int r = 0; r < 4; ++r) { mrow[mi][r] = -3.0e38f; lrow[mi][r] = 0.0f; }

  const int ktEnd = 2 * qt + 1;

#pragma unroll
  for (int j = 0; j < 4; ++j) gll16(kp + ksrc[j], smem + kdst[j]);
#pragma unroll
  for (int j = 0; j < 4; ++j) gll16(vp + vsrc[j], smem + vdst[j]);
  asm volatile("s_waitcnt vmcnt(0)" ::: "memory");
  __builtin_amdgcn_s_barrier();
  __builtin_amdgcn_sched_barrier(0);

  for (int kt = 0; kt <= ktEnd; ++kt) {
    const int kv0 = kt * 64;
    const int cur = kt & 1;

    if (kt < ktEnd) {
      const int nk = (kt + 1) * 64;
      char* nbuf = smem + (cur ^ 1) * 32768;
#pragma unroll
      for (int j = 0; j < 4; ++j) gll16(kp + (size_t)nk * D + ksrc[j], nbuf + kdst[j]);
#pragma unroll
      for (int j = 0; j < 4; ++j) gll16(vp + nk + vsrc[j], nbuf + vdst[j]);
    }

    if (kv0 <= qw + 31) {
      const char* Kb = smem + cur * 32768;
      const char* Vb = Kb + 16384;
      const bool diag = (kv0 + 63 > qw);

      f32x4 sacc[2][4] = {};
#pragma unroll
      for (int kf = 0; kf < 4; ++kf) {
        bf16x8 kfr[4];
#pragma unroll
        for (int ni = 0; ni < 4; ++ni) {
          int row = ni * 16 + ln;
          int ch = (kf * 4 + lm) ^ (row & 7);
          kfr[ni] = *reinterpret_cast<const bf16x8*>(Kb + row * 256 + ch * 16);
        }
        __builtin_amdgcn_s_setprio(1);
#pragma unroll
        for (int mi = 0; mi < 2; ++mi)
#pragma unroll
          for (int ni = 0; ni < 4; ++ni)
            sacc[mi][ni] = mfma16(qf[mi][kf], kfr[ni], sacc[mi][ni]);
        __builtin_amdgcn_s_setprio(0);
      }

      if (diag) {
#pragma unroll
        for (int ni = 0; ni < 4; ++ni) {
          int c = kv0 + ni * 16 + ln;
#pragma unroll
          for (int mi = 0; mi < 2; ++mi) {
            int q0r = qw + mi * 16 + lm * 4;
#pragma unroll
            for (int r = 0; r < 4; ++r)
              if (c > q0r + r) sacc[mi][ni][r] = -1e30f;
          }
        }
      }

#pragma unroll
      for (int mi = 0; mi < 2; ++mi)
#pragma unroll
        for (int r = 0; r < 4; ++r) {
          float mx = fmaxf(fmaxf(sacc[mi][0][r], sacc[mi][1][r]),
                           fmaxf(sacc[mi][2][r], sacc[mi][3][r]));
          mx = fmaxf(mx, __shfl_xor(mx, 1, 64));
          mx = fmaxf(mx, __shfl_xor(mx, 2, 64));
          mx = fmaxf(mx, __shfl_xor(mx, 4, 64));
          mx = fmaxf(mx, __shfl_xor(mx, 8, 64));
          float mnew = fmaxf(mrow[mi][r], mx);
          float corr = __expf(mrow[mi][r] - mnew);
          mrow[mi][r] = mnew;
          float rs = 0.0f;
#pragma unroll
          for (int ni = 0; ni < 4; ++ni) {
            float p = __expf(sacc[mi][ni][r] - mnew);
            sacc[mi][ni][r] = p;
            rs += p;
          }
          lrow[mi][r] = lrow[mi][r] * corr + rs;
#pragma unroll
          for (int ni = 0; ni < 8; ++ni) Oa[mi][ni][r] *= corr;
        }

#pragma unroll
      for (int mi = 0; mi < 2; ++mi)
#pragma unroll
        for (int ni = 0; ni < 4; ++ni)
#pragma unroll
          for (int r = 0; r < 4; ++r) {
            int row = mi * 16 + lm * 4 + r;
            int bo = (row * 128 + (ni * 16 + ln) * 2) ^ ((row & 7) << 4);
            *reinterpret_cast<__bf16*>(pw + bo) = (__bf16)sacc[mi][ni][r];
          }

      asm volatile("s_waitcnt lgkmcnt(0)" ::: "memory");
      __builtin_amdgcn_sched_barrier(0);

#pragma unroll
      for (int kf = 0; kf < 2; ++kf) {
        bf16x8 pfr[2], vfr[8];
#pragma unroll
        for (int mi = 0; mi < 2; ++mi) {
          int row = mi * 16 + ln;
          int ch = (kf * 4 + lm) ^ (row & 7);
          pfr[mi] = *reinterpret_cast<const bf16x8*>(pw + row * 128 + ch * 16);
        }
#pragma unroll
        for (int ni = 0; ni < 8; ++ni) {
          int row = ni * 16 + ln;
          int ch = (kf * 4 + lm) ^ (row & 7);
          vfr[ni] = *reinterpret_cast<const bf16x8*>(Vb + row * 128 + ch * 16);
        }
        __builtin_amdgcn_s_setprio(1);
#pragma unroll
        for (int mi = 0; mi < 2; ++mi)
#pragma unroll
          for (int ni = 0; ni < 8; ++ni)
            Oa[mi][ni] = mfma16(pfr[mi], vfr[ni], Oa[mi][ni]);
        __builtin_amdgcn_s_setprio(0);
      }
    }

    asm volatile("s_waitcnt vmcnt(0) lgkmcnt(0)" ::: "memory");
    __builtin_amdgcn_s_barrier();
    __builtin_amdgcn_sched_barrier(0);
  }

#pragma unroll
  for (int mi = 0; mi < 2; ++mi)
#pragma unroll
    for (int r = 0; r < 4; ++r) {
      float ls = lrow[mi][r];
      ls += __shfl_xor(ls, 1, 64);
      ls += __shfl_xor(ls, 2, 64);
      ls += __shfl_xor(ls, 4, 64);
      ls += __shfl_xor(ls, 8, 64);
      lrow[mi][r] = 1.0f / ls;
    }
  const int b = bh >> 4, h = bh & 15;
#pragma unroll
  for (int mi = 0; mi < 2; ++mi)
#pragma unroll
    for (int ni = 0; ni < 8; ++ni) {
      int d = ni * 16 + ln;
#pragma unroll
      for (int r = 0; r < 4; ++r) {
        int qrow = qw + mi * 16 + lm * 4 + r;
        zb[(size_t)(b * S + qrow) * F + h * D + d] = (__bf16)(Oa[mi][ni][r] * lrow[mi][r]);
      }
    }
}

// ---------------- launch ----------------
extern "C" void kernel_launch(void* const* d_in, const int* in_sizes, int n_in,
                              void* d_out, int out_size, void* d_ws, size_t ws_size,
                              hipStream_t stream) {
  const float* x = (const float*)d_in[0];
  // d_in[1] = causal mask (implemented analytically)
  const float* w_attn = (const float*)d_in[2];
  const float* b_attn = (const float*)d_in[3];
  const float* w_proj = (const float*)d_in[4];
  const float* b_proj = (const float*)d_in[5];
  float* out = (float*)d_out;

  char* ws = (char*)d_ws;
  __bf16* xb    = (__bf16*)(ws + 0);          // 16 MB  [4096][2048] (reused as zb)
  __bf16* wqkv  = (__bf16*)(ws + 16777216);   // 24 MB  [6144][2048] (W^T)
  __bf16* wpro  = (__bf16*)(ws + 41943040);   //  8 MB  [2048][2048] (W^T)
  __bf16* qb    = (__bf16*)(ws + 50331648);   // 16 MB  [bh][s][d]
  __bf16* kb    = (__bf16*)(ws + 67108864);   // 16 MB  [bh][s][d]
  __bf16* vtb   = (__bf16*)(ws + 83886080);   // 16 MB  [bh][d][s]
  __bf16* zb    = xb;  // x fully consumed by QKV GEMM before attention writes z

  (void)hipFuncSetAttribute((const void*)k_gp<128, 384, 4, 0>,
                            hipFuncAttributeMaxDynamicSharedMemorySize, 131072);
  (void)hipFuncSetAttribute((const void*)k_gp<128, 256, 3, 1>,
                            hipFuncAttributeMaxDynamicSharedMemorySize, 98304);
  (void)hipFuncSetAttribute((const void*)k_attn,
                            hipFuncAttributeMaxDynamicSharedMemorySize, 81920);

  k_cvt<<<8192, 256, 0, stream>>>(x, xb);
  k_transpose<<<dim3(96, 32), 256, 0, stream>>>(w_attn, wqkv, 2048, 6144);
  k_transpose<<<dim3(32, 32), 256, 0, stream>>>(w_proj, wpro, 2048, 2048);
  // QKV: M=4096 (32 x 128), N=6144 (16 x 384) -> 512 blocks = 2 exact rounds
  k_gp<128, 384, 4, 0><<<512, 512, 131072, stream>>>(xb, wqkv, b_attn, qb, kb, vtb, nullptr);
  // attention: 512 blocks (complementary-qt balance + XCD affinity inside)
  k_attn<<<512, 256, 81920, stream>>>(qb, kb, vtb, zb);
  // out-proj: M=4096 (32 x 128), N=2048 (8 x 256) -> 256 blocks = 1/CU exact
  k_gp<128, 256, 3, 1><<<256, 512, 98304, stream>>>(zb, wpro, b_proj, nullptr, nullptr, nullptr, out);
}